// Round 4
// baseline (385.457 us; speedup 1.0000x reference)
//
#include <hip/hip_runtime.h>

#define HW  (512*512)

typedef _Float16 half8  __attribute__((__vector_size__(16)));
typedef _Float16 half2_t __attribute__((__vector_size__(4)));
typedef float    floatx4 __attribute__((__vector_size__(16)));

// inline v_exp_f16 (2^x). s_nop 0 guards the 1-wait-state TRANS->consumer
// hazard the compiler can't see through the asm boundary.
__device__ __forceinline__ _Float16 exp2_h(_Float16 x){
    _Float16 r;
    asm("v_exp_f16 %0, %1\n\ts_nop 0" : "=v"(r) : "v"(x));
    return r;
}

__device__ __forceinline__ float sigmoid_f(float x){
    float e = __builtin_amdgcn_exp2f(-1.44269504f * x);
    return __builtin_amdgcn_rcpf(1.0f + e);
}

// packed-f16 gelu (tanh form): x * 1/(1 + exp2(x*(A*x^2+B)))
// saturates correctly at both ends in f16 (inf -> rcp 0; 0 -> rcp 1).
// Verified R3: absmax 3.9e-3, same as f32 path.
__device__ __forceinline__ half2_t gelu_h2(half2_t x){
    const half2_t A   = {(_Float16)-0.1029432f, (_Float16)-0.1029432f};
    const half2_t B   = {(_Float16)-2.3022079f, (_Float16)-2.3022079f};
    const half2_t ONE = {(_Float16)1.0f, (_Float16)1.0f};
    half2_t x2 = x * x;
    half2_t q  = x2 * A + B;        // v_pk_fma_f16
    half2_t u  = x * q;
    half2_t e;
    e[0] = exp2_h(u[0]);            // v_exp_f16 (inlined asm)
    e[1] = exp2_h(u[1]);
    half2_t d = e + ONE;
    half2_t r;
    r[0] = __builtin_amdgcn_rcph(d[0]);
    r[1] = __builtin_amdgcn_rcph(d[1]);
    return x * r;
}

// XOR swizzle: element (row, n) of the 128x256 f16 activation tile lives at
// f16 offset row*256 + (n ^ swz(row)); swz depends only on row&15.
__device__ __forceinline__ int swz(int row){
    return ((row & 3) << 3) ^ (((row >> 2) & 3) << 4);
}

// ---------------- prep: pack weights + per-batch c0, one launch ----------
__global__ void prep_all(const float* __restrict__ W1, const float* __restrict__ W2,
                         const float* __restrict__ W3, const float* __restrict__ emb,
                         const int* __restrict__ sidx, const float* __restrict__ W0,
                         const float* __restrict__ b0,
                         _Float16* __restrict__ wp, float* __restrict__ c0){
    int blk = blockIdx.x;
    int tid = threadIdx.x;
    if (blk < 528){
        int gid = blk * 256 + tid;
        if (gid < 131072){
            int i    = gid & 65535;
            int j    = i & 7;
            int lane = (i >> 3) & 63;
            int b2   = i >> 9;
            int ks = b2 >> 4, nt = b2 & 15;
            int k = ks*32 + ((lane >> 4) << 3) + j;
            int n = nt*16 + (lane & 15);
            const float* W = (gid < 65536) ? W1 : W2;
            wp[gid] = (_Float16)W[k*256 + n];
        } else {
            int i    = gid - 131072;          // 0..4095, W3 padded [256][16]
            int j    = i & 7;
            int lane = (i >> 3) & 63;
            int ks   = i >> 9;                // 0..7
            int k = ks*32 + ((lane >> 4) << 3) + j;
            int n = lane & 15;
            wp[gid] = (_Float16)((n < 3) ? W3[k*3 + n] : 0.0f);
        }
    } else {
        int b = blk - 528;
        int s = sidx[b];
        float acc = b0[tid];
        #pragma unroll 8
        for (int d = 0; d < 64; d++)
            acc = fmaf(emb[s*64 + d], W0[(3 + d)*256 + tid], acc);
        c0[b*256 + tid] = acc;
    }
}

// ---------------- fused MLP ----------------
__global__ __launch_bounds__(512, 4)
void nilut_main(const float* __restrict__ rgb,
                const float* __restrict__ W0,
                const float* __restrict__ b1v,
                const float* __restrict__ b2v,
                const float* __restrict__ b3v,
                const _Float16* __restrict__ wp,
                const float* __restrict__ c0,
                float* __restrict__ out){
    __shared__ __align__(16) _Float16 act[128 * 256];   // 65536 B, XOR-swizzled
    __shared__ __align__(16) float    w0s[1024];        // W0 rows 0..2 | c0[b]; reused as out bounce

    const int tid = threadIdx.x;
    const int wg  = blockIdx.x;
    const int pixbase = wg * 128;
    const int b   = pixbase >> 18;        // HW = 2^18
    const int hw0 = pixbase & (HW - 1);

    // stage W0[0:3] + c0[b] into LDS
    #pragma unroll
    for (int r = 0; r < 2; r++){
        int q = r*512 + tid;
        w0s[q] = (q < 768) ? W0[q] : c0[b*256 + (q - 768)];
    }
    __syncthreads();

    // ---- layer 0 (K=3 VALU + precomputed c0), packed f16 gelu ----
    {
        int row = tid & 127;
        int ch  = tid >> 7;                // col quarter 0..3
        int sr  = swz(row);
        int base = b*3*HW + hw0 + row;
        float rr = rgb[base], gg = rgb[base + HW], bb = rgb[base + 2*HW];
        #pragma unroll
        for (int cg = 0; cg < 8; cg++){
            int nc = ch*64 + cg*8;
            half8 v;
            #pragma unroll
            for (int jp = 0; jp < 4; jp++){
                int n0 = nc + jp*2;
                float z0 = fmaf(rr, w0s[n0],   fmaf(gg, w0s[256 + n0],   fmaf(bb, w0s[512 + n0],   w0s[768 + n0])));
                float z1 = fmaf(rr, w0s[n0+1], fmaf(gg, w0s[256 + n0+1], fmaf(bb, w0s[512 + n0+1], w0s[768 + n0+1])));
                half2_t g = gelu_h2(__builtin_amdgcn_cvt_pkrtz(z0, z1));
                v[jp*2]   = g[0];
                v[jp*2+1] = g[1];
            }
            *(half8*)&act[row*256 + (nc ^ sr)] = v;
        }
    }
    __syncthreads();

    const int lane = tid & 63;
    const int wv   = tid >> 6;            // 0..7
    const int ln15 = lane & 15;
    const int quad = lane >> 4;
    const int q8   = quad * 8;
    const int qr   = quad * 4;
    const int sA   = swz(ln15);           // A-frag swizzle (row&15 == ln15)

    // ---- layers 1 and 2: 256x256 f16 MFMA, 2(row) x 4(col) wave split ----
    const _Float16* wl  = wp;             // Wp1
    const float* bias   = b1v;
    const int mh = wv >> 2, nh = wv & 3;
    const int rbase = mh * 64;
    const int cb16  = nh * 4;             // col base in 16-col units
    #pragma unroll 1
    for (int L = 0; L < 2; L++){
        floatx4 acc[4][4];
        #pragma unroll
        for (int nt = 0; nt < 4; nt++){
            float bv = bias[(cb16 + nt)*16 + ln15];
            #pragma unroll
            for (int m = 0; m < 4; m++)
                acc[m][nt] = (floatx4){bv, bv, bv, bv};
        }

        const half8* wp8 = (const half8*)wl;
        #pragma unroll 2
        for (int ks = 0; ks < 8; ks++){
            int k0 = (ks*32 + q8) ^ sA;
            half8 a[4];
            #pragma unroll
            for (int m = 0; m < 4; m++)
                a[m] = *(const half8*)&act[(rbase + m*16 + ln15)*256 + k0];
            #pragma unroll
            for (int nt = 0; nt < 4; nt++){
                half8 bf = wp8[(ks*16 + cb16 + nt)*64 + lane];
                #pragma unroll
                for (int m = 0; m < 4; m++)
                    acc[m][nt] = __builtin_amdgcn_mfma_f32_16x16x32_f16(a[m], bf, acc[m][nt], 0, 0, 0);
            }
        }
        __syncthreads();   // all reads of act done before overwrite
        #pragma unroll
        for (int nt = 0; nt < 4; nt++){
            int nq = ((cb16 + nt)*16 + ln15) ^ (quad << 4);
            #pragma unroll
            for (int m = 0; m < 4; m++){
                floatx4 vr = acc[m][nt];
                half2_t g0 = gelu_h2(__builtin_amdgcn_cvt_pkrtz(vr[0], vr[1]));
                half2_t g1 = gelu_h2(__builtin_amdgcn_cvt_pkrtz(vr[2], vr[3]));
                int rowb = (rbase + m*16 + qr) * 256;
                act[rowb         + nq       ] = g0[0];
                act[rowb + 256   + (nq ^  8)] = g0[1];
                act[rowb + 512   + (nq ^ 16)] = g1[0];
                act[rowb + 768   + (nq ^ 24)] = g1[1];
            }
        }
        __syncthreads();
        wl = wp + 65536;   // Wp2
        bias = b2v;
    }

    // ---- final layer 256 -> 3 (padded to 16) + sigmoid ----
    {
        const half8* wp8 = (const half8*)(wp + 131072);
        int rbf = wv * 16;                 // 8 waves x 16 rows = 128
        floatx4 ac = (floatx4){0.f,0.f,0.f,0.f};
        #pragma unroll
        for (int ks = 0; ks < 8; ks++){
            int k0 = (ks*32 + q8) ^ sA;
            half8 a  = *(const half8*)&act[(rbf + ln15)*256 + k0];
            half8 bf = wp8[ks*64 + lane];
            ac = __builtin_amdgcn_mfma_f32_16x16x32_f16(a, bf, ac, 0, 0, 0);
        }
        // w0s dead since layer 0 -> reuse as out bounce [3][128]
        if (ln15 < 3){
            float bv = b3v[ln15];
            #pragma unroll
            for (int r = 0; r < 4; r++){
                int row0 = rbf + qr + r;
                w0s[ln15*128 + row0] = sigmoid_f(ac[r] + bv);
            }
        }
        __syncthreads();
        if (tid < 96){
            int c  = tid >> 5;
            int i2 = tid & 31;
            float4* dst = (float4*)(out + (b*3 + c)*HW + hw0);
            dst[i2] = ((float4*)(w0s + c*128))[i2];
        }
    }
}

extern "C" void kernel_launch(void* const* d_in, const int* in_sizes, int n_in,
                              void* d_out, int out_size, void* d_ws, size_t ws_size,
                              hipStream_t stream){
    const float* rgb = (const float*)d_in[0];
    const int*  sidx = (const int*) d_in[1];
    const float* emb = (const float*)d_in[2];
    const float* W0  = (const float*)d_in[3];
    const float* b0  = (const float*)d_in[4];
    const float* W1  = (const float*)d_in[5];
    const float* b1  = (const float*)d_in[6];
    const float* W2  = (const float*)d_in[7];
    const float* b2  = (const float*)d_in[8];
    const float* W3  = (const float*)d_in[9];
    const float* b3  = (const float*)d_in[10];
    float* out = (float*)d_out;

    _Float16* wp = (_Float16*)d_ws;                    // 135168 f16 = 270336 B
    float*    c0 = (float*)((char*)d_ws + 270336);     // 512 f32

    int n_pix = in_sizes[0] / 3;                       // 524288
    prep_all<<<530, 256, 0, stream>>>(W1, W2, W3, emb, sidx, W0, b0, wp, c0);
    nilut_main<<<n_pix / 128, 512, 0, stream>>>(rgb, W0, b1, b2, b3, wp, c0, out);
}

// Round 5
// 285.725 us; speedup vs baseline: 1.3490x; 1.3490x over previous
//
#include <hip/hip_runtime.h>

#define HW  (512*512)

typedef _Float16 half8  __attribute__((__vector_size__(16)));
typedef float    floatx4 __attribute__((__vector_size__(16)));

__device__ __forceinline__ float gelu_f(float x){
    // gelu_tanh(x) = x * sigmoid(2c*(x + 0.044715 x^3)), c = sqrt(2/pi)
    float x2 = x * x;
    float q  = __builtin_fmaf(x2, -0.1029432f, -2.3022079f);
    float e  = __builtin_amdgcn_exp2f(x * q);
    return x * __builtin_amdgcn_rcpf(1.0f + e);
}

__device__ __forceinline__ float sigmoid_f(float x){
    float e = __builtin_amdgcn_exp2f(-1.44269504f * x);
    return __builtin_amdgcn_rcpf(1.0f + e);
}

// XOR swizzle: element (row, n) of the 128x256 f16 activation tile lives at
// f16 offset row*256 + (n ^ swz(row)); swz depends only on row&15.
__device__ __forceinline__ int swz(int row){
    return ((row & 3) << 3) ^ (((row >> 2) & 3) << 4);
}

// ---------------- prep: pack weights + per-batch c0, one launch ----------
__global__ void prep_all(const float* __restrict__ W1, const float* __restrict__ W2,
                         const float* __restrict__ W3, const float* __restrict__ emb,
                         const int* __restrict__ sidx, const float* __restrict__ W0,
                         const float* __restrict__ b0,
                         _Float16* __restrict__ wp, float* __restrict__ c0){
    int blk = blockIdx.x;
    int tid = threadIdx.x;
    if (blk < 528){
        int gid = blk * 256 + tid;
        if (gid < 131072){
            int i    = gid & 65535;
            int j    = i & 7;
            int lane = (i >> 3) & 63;
            int b2   = i >> 9;
            int ks = b2 >> 4, nt = b2 & 15;
            int k = ks*32 + ((lane >> 4) << 3) + j;
            int n = nt*16 + (lane & 15);
            const float* W = (gid < 65536) ? W1 : W2;
            wp[gid] = (_Float16)W[k*256 + n];
        } else {
            int i    = gid - 131072;          // 0..4095, W3 padded [256][16]
            int j    = i & 7;
            int lane = (i >> 3) & 63;
            int ks   = i >> 9;                // 0..7
            int k = ks*32 + ((lane >> 4) << 3) + j;
            int n = lane & 15;
            wp[gid] = (_Float16)((n < 3) ? W3[k*3 + n] : 0.0f);
        }
    } else {
        int b = blk - 528;
        int s = sidx[b];
        float acc = b0[tid];
        #pragma unroll 8
        for (int d = 0; d < 64; d++)
            acc = fmaf(emb[s*64 + d], W0[(3 + d)*256 + tid], acc);
        c0[b*256 + tid] = acc;
    }
}

// ---------------- fused MLP ----------------
__global__ __launch_bounds__(512, 4)
void nilut_main(const float* __restrict__ rgb,
                const float* __restrict__ W0,
                const float* __restrict__ b1v,
                const float* __restrict__ b2v,
                const float* __restrict__ b3v,
                const _Float16* __restrict__ wp,
                const float* __restrict__ c0,
                float* __restrict__ out){
    __shared__ __align__(16) _Float16 act[128 * 256];   // 65536 B, XOR-swizzled
    __shared__ __align__(16) float    w0s[1024];        // W0 rows 0..2 | c0[b]; reused as out bounce
    __shared__ __align__(16) float    rgbs[384];        // staged rgb tile [3][128]

    const int tid = threadIdx.x;
    const int wg  = blockIdx.x;
    const int pixbase = wg * 128;
    const int b   = pixbase >> 18;        // HW = 2^18
    const int hw0 = pixbase & (HW - 1);

    // stage W0[0:3] + c0[b] into LDS
    #pragma unroll
    for (int r = 0; r < 2; r++){
        int q = r*512 + tid;
        w0s[q] = (q < 768) ? W0[q] : c0[b*256 + (q - 768)];
    }
    // stage rgb tile (coalesced: 3 runs of 128 contiguous floats)
    if (tid < 384){
        int c = tid >> 7, row = tid & 127;
        rgbs[tid] = rgb[b*3*HW + c*HW + hw0 + row];
    }
    __syncthreads();

    // ---- layer 0: coeffs in registers, 8 cols x 8 rows per thread ----
    {
        int ng = tid & 31;                // fixed col group: n = ng*8 .. ng*8+7
        int rg = tid >> 5;                // row group: rows rg*8 .. rg*8+7
        floatx4 cw[4][2];
        #pragma unroll
        for (int p = 0; p < 4; p++){
            cw[p][0] = *(const floatx4*)&w0s[p*256 + ng*8];
            cw[p][1] = *(const floatx4*)&w0s[p*256 + ng*8 + 4];
        }
        #pragma unroll
        for (int hf = 0; hf < 2; hf++){
            floatx4 rv[3];
            #pragma unroll
            for (int c = 0; c < 3; c++)
                rv[c] = *(const floatx4*)&rgbs[c*128 + rg*8 + hf*4];
            #pragma unroll
            for (int r4 = 0; r4 < 4; r4++){
                int row = rg*8 + hf*4 + r4;
                float rr = rv[0][r4], gg = rv[1][r4], bb = rv[2][r4];
                half8 v;
                #pragma unroll
                for (int j = 0; j < 8; j++){
                    int hi = j >> 2, lo = j & 3;
                    float z = fmaf(rr, cw[0][hi][lo],
                              fmaf(gg, cw[1][hi][lo],
                              fmaf(bb, cw[2][hi][lo], cw[3][hi][lo])));
                    v[j] = (_Float16)gelu_f(z);
                }
                *(half8*)&act[row*256 + ((ng*8) ^ swz(row))] = v;
            }
        }
    }
    __syncthreads();

    const int lane = tid & 63;
    const int wv   = tid >> 6;            // 0..7
    const int ln15 = lane & 15;
    const int quad = lane >> 4;
    const int q8   = quad * 8;
    const int qr   = quad * 4;
    const int sA   = swz(ln15);           // A-frag swizzle (row&15 == ln15)

    // ---- layers 1 and 2: 256x256 f16 MFMA, 2(row) x 4(col) wave split ----
    const _Float16* wl  = wp;             // Wp1
    const float* bias   = b1v;
    const int mh = wv >> 2, nh = wv & 3;
    const int rbase = mh * 64;
    const int cb16  = nh * 4;             // col base in 16-col units
    #pragma unroll 1
    for (int L = 0; L < 2; L++){
        floatx4 acc[4][4];
        #pragma unroll
        for (int nt = 0; nt < 4; nt++){
            float bv = bias[(cb16 + nt)*16 + ln15];
            #pragma unroll
            for (int m = 0; m < 4; m++)
                acc[m][nt] = (floatx4){bv, bv, bv, bv};
        }

        const half8* wp8 = (const half8*)wl;
        #pragma unroll 2
        for (int ks = 0; ks < 8; ks++){
            int k0 = (ks*32 + q8) ^ sA;
            half8 a[4];
            #pragma unroll
            for (int m = 0; m < 4; m++)
                a[m] = *(const half8*)&act[(rbase + m*16 + ln15)*256 + k0];
            #pragma unroll
            for (int nt = 0; nt < 4; nt++){
                half8 bf = wp8[(ks*16 + cb16 + nt)*64 + lane];
                #pragma unroll
                for (int m = 0; m < 4; m++)
                    acc[m][nt] = __builtin_amdgcn_mfma_f32_16x16x32_f16(a[m], bf, acc[m][nt], 0, 0, 0);
            }
        }
        __syncthreads();   // all reads of act done before overwrite
        #pragma unroll
        for (int nt = 0; nt < 4; nt++){
            int n = (cb16 + nt)*16 + ln15;
            #pragma unroll
            for (int m = 0; m < 4; m++){
                #pragma unroll
                for (int r = 0; r < 4; r++){
                    int row = rbase + m*16 + qr + r;
                    int se  = (r << 3) ^ (quad << 4);   // swz(qr + r)
                    act[row*256 + (n ^ se)] = (_Float16)gelu_f(acc[m][nt][r]);
                }
            }
        }
        __syncthreads();
        wl = wp + 65536;   // Wp2
        bias = b2v;
    }

    // ---- final layer 256 -> 3 (padded to 16) + sigmoid ----
    {
        const half8* wp8 = (const half8*)(wp + 131072);
        int rbf = wv * 16;                 // 8 waves x 16 rows = 128
        floatx4 ac = (floatx4){0.f,0.f,0.f,0.f};
        #pragma unroll
        for (int ks = 0; ks < 8; ks++){
            int k0 = (ks*32 + q8) ^ sA;
            half8 a  = *(const half8*)&act[(rbf + ln15)*256 + k0];
            half8 bf = wp8[ks*64 + lane];
            ac = __builtin_amdgcn_mfma_f32_16x16x32_f16(a, bf, ac, 0, 0, 0);
        }
        // w0s dead since layer 0 -> reuse as out bounce [3][128]
        if (ln15 < 3){
            float bv = b3v[ln15];
            #pragma unroll
            for (int r = 0; r < 4; r++){
                int row0 = rbf + qr + r;
                w0s[ln15*128 + row0] = sigmoid_f(ac[r] + bv);
            }
        }
        __syncthreads();
        if (tid < 96){
            int c  = tid >> 5;
            int i2 = tid & 31;
            float4* dst = (float4*)(out + (b*3 + c)*HW + hw0);
            dst[i2] = ((float4*)(w0s + c*128))[i2];
        }
    }
}

extern "C" void kernel_launch(void* const* d_in, const int* in_sizes, int n_in,
                              void* d_out, int out_size, void* d_ws, size_t ws_size,
                              hipStream_t stream){
    const float* rgb = (const float*)d_in[0];
    const int*  sidx = (const int*) d_in[1];
    const float* emb = (const float*)d_in[2];
    const float* W0  = (const float*)d_in[3];
    const float* b0  = (const float*)d_in[4];
    const float* W1  = (const float*)d_in[5];
    const float* b1  = (const float*)d_in[6];
    const float* W2  = (const float*)d_in[7];
    const float* b2  = (const float*)d_in[8];
    const float* W3  = (const float*)d_in[9];
    const float* b3  = (const float*)d_in[10];
    float* out = (float*)d_out;

    _Float16* wp = (_Float16*)d_ws;                    // 135168 f16 = 270336 B
    float*    c0 = (float*)((char*)d_ws + 270336);     // 512 f32

    int n_pix = in_sizes[0] / 3;                       // 524288
    prep_all<<<530, 256, 0, stream>>>(W1, W2, W3, emb, sidx, W0, b0, wp, c0);
    nilut_main<<<n_pix / 128, 512, 0, stream>>>(rgb, W0, b1, b2, b3, wp, c0, out);
}